// Round 2
// baseline (360.725 us; speedup 1.0000x reference)
//
#include <hip/hip_runtime.h>

// MoE top-2 of 8 experts. B=4,S=2048,D=1024,H=1024,E=8,G=256. N=8192 tokens.
// Outputs: out[8192][1024] fp32, then loss scalar (out_size = 8388609).

#define N_TOK 8192
#define DIM   1024
#define HID   1024
#define NEXP  8
#define GDIM  256
#define NPAIR (N_TOK * 2)
#define HB_ROWS (NPAIR + 256)   // packed pair rows + tile-padding slack
#define MT_MAX 136              // >= max sum_e ceil(cnt_e/128)

typedef __attribute__((ext_vector_type(4))) float    f32x4;
typedef __attribute__((ext_vector_type(8))) _Float16 f16x8;

static __device__ __forceinline__ void async_ld16(const void* g, void* l) {
  __builtin_amdgcn_global_load_lds(
      (const __attribute__((address_space(1))) unsigned int*)g,
      (__attribute__((address_space(3))) unsigned int*)l, 16, 0, 0);
}

// ---------------- cast x: fp32 -> fp16 ----------------
__global__ void cast_x_kernel(const float* __restrict__ x, _Float16* __restrict__ xh) {
  size_t o = ((size_t)blockIdx.x * 256 + threadIdx.x) * 8;
  float4 v0 = *(const float4*)(x + o);
  float4 v1 = *(const float4*)(x + o + 4);
  f16x8 h;
  h[0] = (_Float16)v0.x; h[1] = (_Float16)v0.y; h[2] = (_Float16)v0.z; h[3] = (_Float16)v0.w;
  h[4] = (_Float16)v1.x; h[5] = (_Float16)v1.y; h[6] = (_Float16)v1.z; h[7] = (_Float16)v1.w;
  *(f16x8*)(xh + o) = h;
}

// ------- transpose-cast W_in[e][d][h] -> WinT[e][h][d], W_out[e][h][d] -> WoutT[e][d][h] -------
__global__ void cast_wT_kernel(const float* __restrict__ Win, const float* __restrict__ Wout,
                               _Float16* __restrict__ WinT, _Float16* __restrict__ WoutT) {
  __shared__ float t[32][33];
  int z = blockIdx.z;  // 0..7 -> W_in expert z ; 8..15 -> W_out expert z-8
  const float* src = (z < NEXP ? Win : Wout) + (size_t)(z & 7) * DIM * HID;
  _Float16*    dst = (z < NEXP ? WinT : WoutT) + (size_t)(z & 7) * DIM * HID;
  int i0 = blockIdx.x * 32, j0 = blockIdx.y * 32;
  int tx = threadIdx.x, ty = threadIdx.y;  // (32,8)
#pragma unroll
  for (int q = 0; q < 4; ++q)
    t[ty + q * 8][tx] = src[(size_t)(i0 + ty + q * 8) * 1024 + j0 + tx];
  __syncthreads();
#pragma unroll
  for (int q = 0; q < 4; ++q)
    dst[(size_t)(j0 + ty + q * 8) * 1024 + i0 + tx] = (_Float16)t[tx][ty + q * 8];
}

// ---------------- fp32 tiled GEMM: hg = tanh(x @ Wg1)  [8192x1024]x[1024x256] ----------------
__global__ __launch_bounds__(256) void gemm_h_kernel(const float* __restrict__ x,
                                                     const float* __restrict__ Wg1,
                                                     float* __restrict__ hg) {
  __shared__ float Als[32][68];  // [k][m] transposed, padded
  __shared__ float Bls[32][68];  // [k][n]
  int m0 = blockIdx.x * 64, n0 = blockIdx.y * 64;
  int tid = threadIdx.x;
  int tx = tid & 15, ty = tid >> 4;  // n-thread, m-thread
  float acc[4][4] = {};
  for (int k0 = 0; k0 < DIM; k0 += 32) {
    __syncthreads();
    {
      int m = tid >> 3, k4 = (tid & 7) << 2;
#pragma unroll
      for (int it = 0; it < 2; ++it) {
        float4 v = *(const float4*)&x[(size_t)(m0 + m + it * 32) * DIM + k0 + k4];
        int mm = m + it * 32;
        Als[k4 + 0][mm] = v.x; Als[k4 + 1][mm] = v.y;
        Als[k4 + 2][mm] = v.z; Als[k4 + 3][mm] = v.w;
      }
      int k = tid >> 4, n4 = (tid & 15) << 2;
#pragma unroll
      for (int it = 0; it < 2; ++it)
        *(float4*)&Bls[k + it * 16][n4] =
            *(const float4*)&Wg1[(size_t)(k0 + k + it * 16) * GDIM + n0 + n4];
    }
    __syncthreads();
#pragma unroll
    for (int k = 0; k < 32; ++k) {
      float4 a = *(const float4*)&Als[k][ty << 2];
      float4 b = *(const float4*)&Bls[k][tx << 2];
      float av[4] = {a.x, a.y, a.z, a.w};
      float bv[4] = {b.x, b.y, b.z, b.w};
#pragma unroll
      for (int i = 0; i < 4; ++i)
#pragma unroll
        for (int j = 0; j < 4; ++j) acc[i][j] = fmaf(av[i], bv[j], acc[i][j]);
    }
  }
#pragma unroll
  for (int i = 0; i < 4; ++i) {
    float4 o;
    o.x = tanhf(acc[i][0]); o.y = tanhf(acc[i][1]);
    o.z = tanhf(acc[i][2]); o.w = tanhf(acc[i][3]);
    *(float4*)&hg[(size_t)(m0 + (ty << 2) + i) * GDIM + n0 + (tx << 2)] = o;
  }
}

// ------------- gate: logits = hg@Wg2, softmax, top-2, loss partials, counts -------------
__global__ void gate_kernel(const float* __restrict__ hg, const float* __restrict__ Wg2,
                            int* __restrict__ top_i, float* __restrict__ top_v,
                            float* __restrict__ lossacc, int* __restrict__ counts) {
  __shared__ float psum[8];
  __shared__ float entsum;
  __shared__ int cnts[8];
  int tid = threadIdx.x;
  if (tid < 8) { psum[tid] = 0.f; cnts[tid] = 0; }
  if (tid == 0) entsum = 0.f;
  __syncthreads();
  int token = blockIdx.x * 8 + (tid >> 5);
  int lane = tid & 31;
  const float* hrow = hg + (size_t)token * GDIM;
  float lg[8] = {0, 0, 0, 0, 0, 0, 0, 0};
#pragma unroll
  for (int j = 0; j < 8; ++j) {
    int g = lane + (j << 5);
    float hv = hrow[g];
#pragma unroll
    for (int e = 0; e < 8; ++e) lg[e] = fmaf(hv, Wg2[g * 8 + e], lg[e]);
  }
#pragma unroll
  for (int e = 0; e < 8; ++e) {
    lg[e] += __shfl_xor(lg[e], 16);
    lg[e] += __shfl_xor(lg[e], 8);
    lg[e] += __shfl_xor(lg[e], 4);
    lg[e] += __shfl_xor(lg[e], 2);
    lg[e] += __shfl_xor(lg[e], 1);
  }
  if (lane == 0) {
    float mx = lg[0];
#pragma unroll
    for (int e = 1; e < 8; ++e) mx = fmaxf(mx, lg[e]);
    float p[8], s = 0.f;
#pragma unroll
    for (int e = 0; e < 8; ++e) { p[e] = expf(lg[e] - mx); s += p[e]; }
    float inv = 1.f / s, ent = 0.f;
    int i0 = 0, i1 = 0;
    float v0 = -1.f, v1 = -1.f;
#pragma unroll
    for (int e = 0; e < 8; ++e) {
      p[e] *= inv;
      ent += p[e] * logf(p[e] + 1e-9f);
      if (p[e] > v0)      { v1 = v0; i1 = i0; v0 = p[e]; i0 = e; }
      else if (p[e] > v1) { v1 = p[e]; i1 = e; }
    }
    top_i[token * 2 + 0] = i0; top_i[token * 2 + 1] = i1;
    top_v[token * 2 + 0] = v0; top_v[token * 2 + 1] = v1;
#pragma unroll
    for (int e = 0; e < 8; ++e) atomicAdd(&psum[e], p[e]);
    atomicAdd(&entsum, ent);
    atomicAdd(&cnts[i0], 1);
    atomicAdd(&cnts[i1], 1);
  }
  __syncthreads();
  if (tid < 8) { atomicAdd(&lossacc[tid], psum[tid]); atomicAdd(&counts[tid], cnts[tid]); }
  if (tid == 8) atomicAdd(&lossacc[8], entsum);
}

// ---------------- scan: offsets from counts ----------------
__global__ void scan_kernel(const int* __restrict__ counts, int* __restrict__ offsets) {
  if (threadIdx.x == 0) {
    int acc = 0;
#pragma unroll
    for (int e = 0; e < 8; ++e) { offsets[e] = acc; acc += counts[e]; }
    offsets[8] = acc;
  }
}

// ---------------- fill packed per-expert pair lists ----------------
__global__ void fill_kernel(const int* __restrict__ top_i, const float* __restrict__ top_v,
                            const int* __restrict__ offsets, int* __restrict__ cursors,
                            int* __restrict__ ptok, float* __restrict__ pgate) {
  int n = blockIdx.x * 256 + threadIdx.x;
#pragma unroll
  for (int s = 0; s < 2; ++s) {
    int e = top_i[n * 2 + s];
    int p = atomicAdd(&cursors[e], 1);
    int r = offsets[e] + p;
    ptok[r] = n;
    pgate[r] = top_v[n * 2 + s];
  }
}

// ---------------- grouped GEMM1: hb[r][h] = relu(x[tok_r] @ W_in[e]) ----------------
__global__ __launch_bounds__(256) void gemm1_kernel(const _Float16* __restrict__ xh,
                                                    const _Float16* __restrict__ WinT,
                                                    _Float16* __restrict__ hb,
                                                    const int* __restrict__ offsets,
                                                    const int* __restrict__ ptok) {
  __shared__ __align__(16) _Float16 Als[128 * 32];
  __shared__ __align__(16) _Float16 Bls[128 * 32];
  int loc = blockIdx.x;
  int base = 0, cnt = 0, e;
  for (e = 0; e < NEXP; ++e) {
    base = offsets[e];
    cnt = offsets[e + 1] - base;
    int mts = (cnt + 127) >> 7;
    if (loc < mts) break;
    loc -= mts;
  }
  if (e == NEXP) return;
  int row0 = base + (loc << 7);
  int rmax = cnt - (loc << 7);   // valid rows in THIS tile (1..128)
  int n0 = blockIdx.y << 7;
  int tid = threadIdx.x, wave = tid >> 6, lane = tid & 63;
  int wr = (wave >> 1) << 6, wc = (wave & 1) << 6;

  size_t asrc[2], bsrc[2];
  const _Float16* WB = WinT + (size_t)e * DIM * HID;
#pragma unroll
  for (int j = 0; j < 2; ++j) {
    int r = wave * 32 + j * 16 + (lane >> 2);
    // FIX (round 1): guard is r < rmax (per-tile), NOT r < cnt. The old guard let
    // last-tile pad rows read past ptok[] into pgate floats -> ~1e9 "token" -> page fault.
    int tok = ptok[(r < rmax) ? (row0 + r) : base];
    asrc[j] = (size_t)tok * DIM + ((lane & 3) << 3);
    bsrc[j] = (size_t)(n0 + r) * DIM + ((lane & 3) << 3);  // same r formula reused as col index
  }
  f32x4 acc[4][4] = {};

  for (int k0 = 0; k0 < DIM; k0 += 32) {
    __syncthreads();
#pragma unroll
    for (int j = 0; j < 2; ++j) {
      async_ld16(xh + asrc[j] + k0, Als + (size_t)(wave * 128 + j * 64) * 8);
      async_ld16(WB + bsrc[j] + k0, Bls + (size_t)(wave * 128 + j * 64) * 8);
    }
    __syncthreads();
    f16x8 a[4], b[4];
#pragma unroll
    for (int m = 0; m < 4; ++m)
      a[m] = *(const f16x8*)&Als[(wr + m * 16 + (lane & 15)) * 32 + ((lane >> 4) << 3)];
#pragma unroll
    for (int n = 0; n < 4; ++n)
      b[n] = *(const f16x8*)&Bls[(wc + n * 16 + (lane & 15)) * 32 + ((lane >> 4) << 3)];
#pragma unroll
    for (int m = 0; m < 4; ++m)
#pragma unroll
      for (int n = 0; n < 4; ++n)
        acc[m][n] = __builtin_amdgcn_mfma_f32_16x16x32_f16(a[m], b[n], acc[m][n], 0, 0, 0);
  }
#pragma unroll
  for (int m = 0; m < 4; ++m) {
#pragma unroll
    for (int i = 0; i < 4; ++i) {
      int r = wr + m * 16 + ((lane >> 4) << 2) + i;
      if (r < rmax) {
        _Float16* hrow = hb + (size_t)(row0 + r) * HID;
#pragma unroll
        for (int n = 0; n < 4; ++n)
          hrow[n0 + wc + n * 16 + (lane & 15)] = (_Float16)fmaxf(acc[m][n][i], 0.f);
      }
    }
  }
}

// ---------------- grouped GEMM2: out[tok] += gate * (hb[r] @ W_out[e]) ----------------
__global__ __launch_bounds__(256) void gemm2_kernel(const _Float16* __restrict__ hb,
                                                    const _Float16* __restrict__ WoutT,
                                                    float* __restrict__ out,
                                                    const int* __restrict__ offsets,
                                                    const int* __restrict__ ptok,
                                                    const float* __restrict__ pgate) {
  __shared__ __align__(16) _Float16 Als[128 * 32];
  __shared__ __align__(16) _Float16 Bls[128 * 32];
  int loc = blockIdx.x;
  int base = 0, cnt = 0, e;
  for (e = 0; e < NEXP; ++e) {
    base = offsets[e];
    cnt = offsets[e + 1] - base;
    int mts = (cnt + 127) >> 7;
    if (loc < mts) break;
    loc -= mts;
  }
  if (e == NEXP) return;
  int row0 = base + (loc << 7);
  int rmax = cnt - (loc << 7);
  int n0 = blockIdx.y << 7;
  int tid = threadIdx.x, wave = tid >> 6, lane = tid & 63;
  int wr = (wave >> 1) << 6, wc = (wave & 1) << 6;

  size_t asrc[2], bsrc[2];
  const _Float16* WB = WoutT + (size_t)e * DIM * HID;
#pragma unroll
  for (int j = 0; j < 2; ++j) {
    int r = wave * 32 + j * 16 + (lane >> 2);
    asrc[j] = (size_t)(row0 + r) * HID + ((lane & 3) << 3);  // hb has +256 rows slack: in-bounds
    bsrc[j] = (size_t)(n0 + r) * DIM + ((lane & 3) << 3);
  }
  f32x4 acc[4][4] = {};

  for (int k0 = 0; k0 < HID; k0 += 32) {
    __syncthreads();
#pragma unroll
    for (int j = 0; j < 2; ++j) {
      async_ld16(hb + asrc[j] + k0, Als + (size_t)(wave * 128 + j * 64) * 8);
      async_ld16(WB + bsrc[j] + k0, Bls + (size_t)(wave * 128 + j * 64) * 8);
    }
    __syncthreads();
    f16x8 a[4], b[4];
#pragma unroll
    for (int m = 0; m < 4; ++m)
      a[m] = *(const f16x8*)&Als[(wr + m * 16 + (lane & 15)) * 32 + ((lane >> 4) << 3)];
#pragma unroll
    for (int n = 0; n < 4; ++n)
      b[n] = *(const f16x8*)&Bls[(wc + n * 16 + (lane & 15)) * 32 + ((lane >> 4) << 3)];
#pragma unroll
    for (int m = 0; m < 4; ++m)
#pragma unroll
      for (int n = 0; n < 4; ++n)
        acc[m][n] = __builtin_amdgcn_mfma_f32_16x16x32_f16(a[m], b[n], acc[m][n], 0, 0, 0);
  }
#pragma unroll
  for (int m = 0; m < 4; ++m) {
#pragma unroll
    for (int i = 0; i < 4; ++i) {
      int r = wr + m * 16 + ((lane >> 4) << 2) + i;
      if (r < rmax) {
        int gr = row0 + r;
        int tok = ptok[gr];
        float gv = pgate[gr];
        float* orow = out + (size_t)tok * DIM;
#pragma unroll
        for (int n = 0; n < 4; ++n)
          atomicAdd(&orow[n0 + wc + n * 16 + (lane & 15)], gv * acc[m][n][i]);
      }
    }
  }
}

// ---------------- finalize MI loss ----------------
__global__ void loss_kernel(const float* __restrict__ lossacc, float* __restrict__ dst) {
  if (threadIdx.x == 0 && blockIdx.x == 0) {
    float t1 = 0.f;
#pragma unroll
    for (int e = 0; e < 8; ++e) {
      float pm = lossacc[e] * (1.f / (float)N_TOK);
      t1 += pm * logf(pm + 1e-9f);
    }
    dst[0] = t1 - lossacc[8] * (1.f / (float)N_TOK);
  }
}

extern "C" void kernel_launch(void* const* d_in, const int* in_sizes, int n_in,
                              void* d_out, int out_size, void* d_ws, size_t ws_size,
                              hipStream_t stream) {
  const float* x    = (const float*)d_in[0];
  const float* Wg1  = (const float*)d_in[1];
  const float* Wg2  = (const float*)d_in[2];
  const float* Win  = (const float*)d_in[3];
  const float* Wout = (const float*)d_in[4];
  float* out = (float*)d_out;

  char* ws = (char*)d_ws;
  size_t off = 0;
  auto alloc = [&](size_t bytes) -> void* {
    void* p = ws + off;
    off = (off + bytes + 255) & ~(size_t)255;
    return p;
  };
  int*   counts  = (int*)alloc(32);
  int*   offsets = (int*)alloc(64);
  int*   cursors = (int*)alloc(32);
  float* lossacc = (float*)alloc(64);   // header ends at 1024 bytes
  int*   top_i   = (int*)alloc((size_t)NPAIR * 4);
  float* top_v   = (float*)alloc((size_t)NPAIR * 4);
  int*   ptok    = (int*)alloc((size_t)NPAIR * 4);
  float* pgate   = (float*)alloc((size_t)NPAIR * 4);
  float* hg      = (float*)alloc((size_t)N_TOK * GDIM * 4);
  _Float16* xh    = (_Float16*)alloc((size_t)N_TOK * DIM * 2);
  _Float16* WinT  = (_Float16*)alloc((size_t)NEXP * DIM * HID * 2);
  _Float16* WoutT = (_Float16*)alloc((size_t)NEXP * DIM * HID * 2);
  _Float16* hb    = (_Float16*)alloc((size_t)HB_ROWS * HID * 2);
  (void)ws_size; (void)in_sizes; (void)n_in;  // total ws use ~93 MB

  hipMemsetAsync(d_out, 0, (size_t)out_size * sizeof(float), stream);
  hipMemsetAsync(d_ws, 0, 1024, stream);

  cast_x_kernel<<<N_TOK * DIM / (8 * 256), 256, 0, stream>>>(x, xh);
  cast_wT_kernel<<<dim3(32, 32, 16), dim3(32, 8), 0, stream>>>(Win, Wout, WinT, WoutT);
  gemm_h_kernel<<<dim3(N_TOK / 64, GDIM / 64), 256, 0, stream>>>(x, Wg1, hg);
  gate_kernel<<<N_TOK / 8, 256, 0, stream>>>(hg, Wg2, top_i, top_v, lossacc, counts);
  scan_kernel<<<1, 32, 0, stream>>>(counts, offsets);
  fill_kernel<<<N_TOK / 256, 256, 0, stream>>>(top_i, top_v, offsets, cursors, ptok, pgate);
  gemm1_kernel<<<dim3(MT_MAX, HID / 128), 256, 0, stream>>>(xh, WinT, hb, offsets, ptok);
  gemm2_kernel<<<dim3(MT_MAX, DIM / 128), 256, 0, stream>>>(hb, WoutT, out, offsets, ptok, pgate);
  loss_kernel<<<1, 64, 0, stream>>>(lossacc, out + (size_t)N_TOK * DIM);
}

// Round 3
// 329.742 us; speedup vs baseline: 1.0940x; 1.0940x over previous
//
#include <hip/hip_runtime.h>

// MoE top-2 of 8 experts. B=4,S=2048,D=1024,H=1024,E=8,G=256. N=8192 tokens.
// Outputs: out[8192][1024] fp32, then loss scalar (out_size = 8388609).

#define N_TOK 8192
#define DIM   1024
#define HID   1024
#define NEXP  8
#define GDIM  256
#define NPAIR (N_TOK * 2)
#define HB_ROWS (NPAIR + 256)   // packed pair rows + tile-padding slack
#define MT_MAX 136              // >= max sum_e ceil(cnt_e/128)

typedef __attribute__((ext_vector_type(4))) float    f32x4;
typedef __attribute__((ext_vector_type(8))) _Float16 f16x8;

static __device__ __forceinline__ void async_ld16(const void* g, void* l) {
  __builtin_amdgcn_global_load_lds(
      (const __attribute__((address_space(1))) unsigned int*)g,
      (__attribute__((address_space(3))) unsigned int*)l, 16, 0, 0);
}

// ---------------- cast x: fp32 -> fp16 ----------------
__global__ void cast_x_kernel(const float* __restrict__ x, _Float16* __restrict__ xh) {
  size_t o = ((size_t)blockIdx.x * 256 + threadIdx.x) * 8;
  float4 v0 = *(const float4*)(x + o);
  float4 v1 = *(const float4*)(x + o + 4);
  f16x8 h;
  h[0] = (_Float16)v0.x; h[1] = (_Float16)v0.y; h[2] = (_Float16)v0.z; h[3] = (_Float16)v0.w;
  h[4] = (_Float16)v1.x; h[5] = (_Float16)v1.y; h[6] = (_Float16)v1.z; h[7] = (_Float16)v1.w;
  *(f16x8*)(xh + o) = h;
}

// ------- transpose-cast W_in[e][d][h] -> WinT[e][h][d], W_out[e][h][d] -> WoutT[e][d][h] -------
// 64x64 fp32 LDS tile, f16x8 vector stores (old version did scalar 2B stores).
__global__ __launch_bounds__(256) void cast_wT_kernel(const float* __restrict__ Win,
                                                      const float* __restrict__ Wout,
                                                      _Float16* __restrict__ WinT,
                                                      _Float16* __restrict__ WoutT) {
  __shared__ float t[64][65];
  int z = blockIdx.z;  // 0..7 -> W_in expert z ; 8..15 -> W_out expert z-8
  const float* src = (z < NEXP ? Win : Wout) + (size_t)(z & 7) * DIM * HID;
  _Float16*    dst = (z < NEXP ? WinT : WoutT) + (size_t)(z & 7) * DIM * HID;
  int i0 = blockIdx.x * 64, j0 = blockIdx.y * 64;
  int tid = threadIdx.x;
  int col4 = tid & 15, ib = tid >> 4;  // 16 float4 cols, 16 row groups
#pragma unroll
  for (int q = 0; q < 4; ++q) {
    int i = ib * 4 + q;
    *(float4*)&t[i][col4 * 4] = *(const float4*)&src[(size_t)(i0 + i) * 1024 + j0 + col4 * 4];
  }
  __syncthreads();
#pragma unroll
  for (int q = 0; q < 2; ++q) {
    int c = tid * 2 + q;          // 0..511
    int j = c >> 3, i8 = (c & 7) * 8;
    f16x8 h;
#pragma unroll
    for (int k = 0; k < 8; ++k) h[k] = (_Float16)t[i8 + k][j];
    *(f16x8*)&dst[(size_t)(j0 + j) * 1024 + i0 + i8] = h;
  }
}

// ---------------- fp32 tiled GEMM: hg = tanh(x @ Wg1)  [8192x1024]x[1024x256] ----------------
__global__ __launch_bounds__(256) void gemm_h_kernel(const float* __restrict__ x,
                                                     const float* __restrict__ Wg1,
                                                     float* __restrict__ hg) {
  __shared__ float Als[32][68];  // [k][m] transposed, padded
  __shared__ float Bls[32][68];  // [k][n]
  int m0 = blockIdx.x * 64, n0 = blockIdx.y * 64;
  int tid = threadIdx.x;
  int tx = tid & 15, ty = tid >> 4;  // n-thread, m-thread
  float acc[4][4] = {};
  for (int k0 = 0; k0 < DIM; k0 += 32) {
    __syncthreads();
    {
      int m = tid >> 3, k4 = (tid & 7) << 2;
#pragma unroll
      for (int it = 0; it < 2; ++it) {
        float4 v = *(const float4*)&x[(size_t)(m0 + m + it * 32) * DIM + k0 + k4];
        int mm = m + it * 32;
        Als[k4 + 0][mm] = v.x; Als[k4 + 1][mm] = v.y;
        Als[k4 + 2][mm] = v.z; Als[k4 + 3][mm] = v.w;
      }
      int k = tid >> 4, n4 = (tid & 15) << 2;
#pragma unroll
      for (int it = 0; it < 2; ++it)
        *(float4*)&Bls[k + it * 16][n4] =
            *(const float4*)&Wg1[(size_t)(k0 + k + it * 16) * GDIM + n0 + n4];
    }
    __syncthreads();
#pragma unroll
    for (int k = 0; k < 32; ++k) {
      float4 a = *(const float4*)&Als[k][ty << 2];
      float4 b = *(const float4*)&Bls[k][tx << 2];
      float av[4] = {a.x, a.y, a.z, a.w};
      float bv[4] = {b.x, b.y, b.z, b.w};
#pragma unroll
      for (int i = 0; i < 4; ++i)
#pragma unroll
        for (int j = 0; j < 4; ++j) acc[i][j] = fmaf(av[i], bv[j], acc[i][j]);
    }
  }
#pragma unroll
  for (int i = 0; i < 4; ++i) {
    float4 o;
    o.x = tanhf(acc[i][0]); o.y = tanhf(acc[i][1]);
    o.z = tanhf(acc[i][2]); o.w = tanhf(acc[i][3]);
    *(float4*)&hg[(size_t)(m0 + (ty << 2) + i) * GDIM + n0 + (tx << 2)] = o;
  }
}

// ------------- gate: logits = hg@Wg2, softmax, top-2, loss partials, counts -------------
__global__ void gate_kernel(const float* __restrict__ hg, const float* __restrict__ Wg2,
                            int* __restrict__ top_i, float* __restrict__ top_v,
                            float* __restrict__ lossacc, int* __restrict__ counts) {
  __shared__ float psum[8];
  __shared__ float entsum;
  __shared__ int cnts[8];
  int tid = threadIdx.x;
  if (tid < 8) { psum[tid] = 0.f; cnts[tid] = 0; }
  if (tid == 0) entsum = 0.f;
  __syncthreads();
  int token = blockIdx.x * 8 + (tid >> 5);
  int lane = tid & 31;
  const float* hrow = hg + (size_t)token * GDIM;
  float lg[8] = {0, 0, 0, 0, 0, 0, 0, 0};
#pragma unroll
  for (int j = 0; j < 8; ++j) {
    int g = lane + (j << 5);
    float hv = hrow[g];
#pragma unroll
    for (int e = 0; e < 8; ++e) lg[e] = fmaf(hv, Wg2[g * 8 + e], lg[e]);
  }
#pragma unroll
  for (int e = 0; e < 8; ++e) {
    lg[e] += __shfl_xor(lg[e], 16);
    lg[e] += __shfl_xor(lg[e], 8);
    lg[e] += __shfl_xor(lg[e], 4);
    lg[e] += __shfl_xor(lg[e], 2);
    lg[e] += __shfl_xor(lg[e], 1);
  }
  if (lane == 0) {
    float mx = lg[0];
#pragma unroll
    for (int e = 1; e < 8; ++e) mx = fmaxf(mx, lg[e]);
    float p[8], s = 0.f;
#pragma unroll
    for (int e = 0; e < 8; ++e) { p[e] = expf(lg[e] - mx); s += p[e]; }
    float inv = 1.f / s, ent = 0.f;
    int i0 = 0, i1 = 0;
    float v0 = -1.f, v1 = -1.f;
#pragma unroll
    for (int e = 0; e < 8; ++e) {
      p[e] *= inv;
      ent += p[e] * logf(p[e] + 1e-9f);
      if (p[e] > v0)      { v1 = v0; i1 = i0; v0 = p[e]; i0 = e; }
      else if (p[e] > v1) { v1 = p[e]; i1 = e; }
    }
    top_i[token * 2 + 0] = i0; top_i[token * 2 + 1] = i1;
    top_v[token * 2 + 0] = v0; top_v[token * 2 + 1] = v1;
#pragma unroll
    for (int e = 0; e < 8; ++e) atomicAdd(&psum[e], p[e]);
    atomicAdd(&entsum, ent);
    atomicAdd(&cnts[i0], 1);
    atomicAdd(&cnts[i1], 1);
  }
  __syncthreads();
  if (tid < 8) { atomicAdd(&lossacc[tid], psum[tid]); atomicAdd(&counts[tid], cnts[tid]); }
  if (tid == 8) atomicAdd(&lossacc[8], entsum);
}

// ---------------- scan: offsets from counts ----------------
__global__ void scan_kernel(const int* __restrict__ counts, int* __restrict__ offsets) {
  if (threadIdx.x == 0) {
    int acc = 0;
#pragma unroll
    for (int e = 0; e < 8; ++e) { offsets[e] = acc; acc += counts[e]; }
    offsets[8] = acc;
  }
}

// ---------------- fill packed per-expert pair lists (+ inverse map rowof) ----------------
__global__ void fill_kernel(const int* __restrict__ top_i, const float* __restrict__ top_v,
                            const int* __restrict__ offsets, int* __restrict__ cursors,
                            int* __restrict__ ptok, float* __restrict__ pgate,
                            int* __restrict__ rowof) {
  int n = blockIdx.x * 256 + threadIdx.x;
#pragma unroll
  for (int s = 0; s < 2; ++s) {
    int e = top_i[n * 2 + s];
    int p = atomicAdd(&cursors[e], 1);
    int r = offsets[e] + p;
    ptok[r] = n;
    pgate[r] = top_v[n * 2 + s];
    rowof[n * 2 + s] = r;
  }
}

// LDS bank-conflict swizzle (T2/m173 style): gload_lds writes linearly, so we
// pre-swizzle the GLOBAL source column and apply the same XOR on the LDS read.
// slot(row,k16) = k16 ^ ((row>>2)&3). Read bank-starts spread over 8 banks -> 2-way (free).
// Staging lane: row&15 = lane>>2  => xor = lane>>4.   Read: row&15 = lane&15 => xor = (lane>>2)&3.

// ---------------- grouped GEMM1: hb[r][h] = relu(x[tok_r] @ W_in[e]) ----------------
__global__ __launch_bounds__(256) void gemm1_kernel(const _Float16* __restrict__ xh,
                                                    const _Float16* __restrict__ WinT,
                                                    _Float16* __restrict__ hb,
                                                    const int* __restrict__ offsets,
                                                    const int* __restrict__ ptok) {
  __shared__ __align__(16) _Float16 Als[128 * 32];
  __shared__ __align__(16) _Float16 Bls[128 * 32];
  int loc = blockIdx.x;
  int base = 0, cnt = 0, e;
  for (e = 0; e < NEXP; ++e) {
    base = offsets[e];
    cnt = offsets[e + 1] - base;
    int mts = (cnt + 127) >> 7;
    if (loc < mts) break;
    loc -= mts;
  }
  if (e == NEXP) return;
  int row0 = base + (loc << 7);
  int rmax = cnt - (loc << 7);   // valid rows in THIS tile (1..128)
  int n0 = blockIdx.y << 7;
  int tid = threadIdx.x, wave = tid >> 6, lane = tid & 63;
  int wr = (wave >> 1) << 6, wc = (wave & 1) << 6;

  size_t asrc[2], bsrc[2];
  const _Float16* WB = WinT + (size_t)e * DIM * HID;
  int scol = (((lane & 3) ^ (lane >> 4)) << 3);  // swizzled source column (halves)
#pragma unroll
  for (int j = 0; j < 2; ++j) {
    int r = wave * 32 + j * 16 + (lane >> 2);
    int tok = ptok[(r < rmax) ? (row0 + r) : base];
    asrc[j] = (size_t)tok * DIM + scol;
    bsrc[j] = (size_t)(n0 + r) * DIM + scol;
  }
  int rdoff = ((lane >> 4) ^ ((lane >> 2) & 3)) << 3;  // swizzled read offset (halves)
  f32x4 acc[4][4] = {};

  for (int k0 = 0; k0 < DIM; k0 += 32) {
    __syncthreads();
#pragma unroll
    for (int j = 0; j < 2; ++j) {
      async_ld16(xh + asrc[j] + k0, Als + (size_t)(wave * 128 + j * 64) * 8);
      async_ld16(WB + bsrc[j] + k0, Bls + (size_t)(wave * 128 + j * 64) * 8);
    }
    __syncthreads();
    f16x8 a[4], b[4];
#pragma unroll
    for (int m = 0; m < 4; ++m)
      a[m] = *(const f16x8*)&Als[(wr + m * 16 + (lane & 15)) * 32 + rdoff];
#pragma unroll
    for (int n = 0; n < 4; ++n)
      b[n] = *(const f16x8*)&Bls[(wc + n * 16 + (lane & 15)) * 32 + rdoff];
#pragma unroll
    for (int m = 0; m < 4; ++m)
#pragma unroll
      for (int n = 0; n < 4; ++n)
        acc[m][n] = __builtin_amdgcn_mfma_f32_16x16x32_f16(a[m], b[n], acc[m][n], 0, 0, 0);
  }
#pragma unroll
  for (int m = 0; m < 4; ++m) {
#pragma unroll
    for (int i = 0; i < 4; ++i) {
      int r = wr + m * 16 + ((lane >> 4) << 2) + i;
      if (r < rmax) {
        _Float16* hrow = hb + (size_t)(row0 + r) * HID;
#pragma unroll
        for (int n = 0; n < 4; ++n)
          hrow[n0 + wc + n * 16 + (lane & 15)] = (_Float16)fmaxf(acc[m][n][i], 0.f);
      }
    }
  }
}

// ---------------- grouped GEMM2: yb[r][d] = gate_r * (hb[r] @ W_out[e])  (no atomics) ----------------
__global__ __launch_bounds__(256) void gemm2_kernel(const _Float16* __restrict__ hb,
                                                    const _Float16* __restrict__ WoutT,
                                                    _Float16* __restrict__ yb,
                                                    const int* __restrict__ offsets,
                                                    const float* __restrict__ pgate) {
  __shared__ __align__(16) _Float16 Als[128 * 32];
  __shared__ __align__(16) _Float16 Bls[128 * 32];
  int loc = blockIdx.x;
  int base = 0, cnt = 0, e;
  for (e = 0; e < NEXP; ++e) {
    base = offsets[e];
    cnt = offsets[e + 1] - base;
    int mts = (cnt + 127) >> 7;
    if (loc < mts) break;
    loc -= mts;
  }
  if (e == NEXP) return;
  int row0 = base + (loc << 7);
  int rmax = cnt - (loc << 7);
  int n0 = blockIdx.y << 7;
  int tid = threadIdx.x, wave = tid >> 6, lane = tid & 63;
  int wr = (wave >> 1) << 6, wc = (wave & 1) << 6;

  size_t asrc[2], bsrc[2];
  const _Float16* WB = WoutT + (size_t)e * DIM * HID;
  int scol = (((lane & 3) ^ (lane >> 4)) << 3);
#pragma unroll
  for (int j = 0; j < 2; ++j) {
    int r = wave * 32 + j * 16 + (lane >> 2);
    asrc[j] = (size_t)(row0 + r) * HID + scol;  // hb has +256 rows slack: in-bounds
    bsrc[j] = (size_t)(n0 + r) * DIM + scol;
  }
  int rdoff = ((lane >> 4) ^ ((lane >> 2) & 3)) << 3;
  f32x4 acc[4][4] = {};

  for (int k0 = 0; k0 < HID; k0 += 32) {
    __syncthreads();
#pragma unroll
    for (int j = 0; j < 2; ++j) {
      async_ld16(hb + asrc[j] + k0, Als + (size_t)(wave * 128 + j * 64) * 8);
      async_ld16(WB + bsrc[j] + k0, Bls + (size_t)(wave * 128 + j * 64) * 8);
    }
    __syncthreads();
    f16x8 a[4], b[4];
#pragma unroll
    for (int m = 0; m < 4; ++m)
      a[m] = *(const f16x8*)&Als[(wr + m * 16 + (lane & 15)) * 32 + rdoff];
#pragma unroll
    for (int n = 0; n < 4; ++n)
      b[n] = *(const f16x8*)&Bls[(wc + n * 16 + (lane & 15)) * 32 + rdoff];
#pragma unroll
    for (int m = 0; m < 4; ++m)
#pragma unroll
      for (int n = 0; n < 4; ++n)
        acc[m][n] = __builtin_amdgcn_mfma_f32_16x16x32_f16(a[m], b[n], acc[m][n], 0, 0, 0);
  }
#pragma unroll
  for (int m = 0; m < 4; ++m) {
#pragma unroll
    for (int i = 0; i < 4; ++i) {
      int r = wr + m * 16 + ((lane >> 4) << 2) + i;
      if (r < rmax) {
        int gr = row0 + r;
        float gv = pgate[gr];
        _Float16* yrow = yb + (size_t)gr * DIM;
#pragma unroll
        for (int n = 0; n < 4; ++n)
          yrow[n0 + wc + n * 16 + (lane & 15)] = (_Float16)(gv * acc[m][n][i]);
      }
    }
  }
}

// ---------------- combine: out[n] = yb[rowof[2n]] + yb[rowof[2n+1]] ----------------
__global__ __launch_bounds__(256) void combine_kernel(const _Float16* __restrict__ yb,
                                                      const int* __restrict__ rowof,
                                                      float* __restrict__ out) {
  int tid = threadIdx.x;
  int token = blockIdx.x * 2 + (tid >> 7);
  int d0 = (tid & 127) * 8;
  int r0 = rowof[token * 2 + 0];
  int r1 = rowof[token * 2 + 1];
  f16x8 a = *(const f16x8*)&yb[(size_t)r0 * DIM + d0];
  f16x8 b = *(const f16x8*)&yb[(size_t)r1 * DIM + d0];
  float* orow = out + (size_t)token * DIM + d0;
  float4 o0, o1;
  o0.x = (float)a[0] + (float)b[0]; o0.y = (float)a[1] + (float)b[1];
  o0.z = (float)a[2] + (float)b[2]; o0.w = (float)a[3] + (float)b[3];
  o1.x = (float)a[4] + (float)b[4]; o1.y = (float)a[5] + (float)b[5];
  o1.z = (float)a[6] + (float)b[6]; o1.w = (float)a[7] + (float)b[7];
  *(float4*)orow = o0;
  *(float4*)(orow + 4) = o1;
}

// ---------------- finalize MI loss ----------------
__global__ void loss_kernel(const float* __restrict__ lossacc, float* __restrict__ dst) {
  if (threadIdx.x == 0 && blockIdx.x == 0) {
    float t1 = 0.f;
#pragma unroll
    for (int e = 0; e < 8; ++e) {
      float pm = lossacc[e] * (1.f / (float)N_TOK);
      t1 += pm * logf(pm + 1e-9f);
    }
    dst[0] = t1 - lossacc[8] * (1.f / (float)N_TOK);
  }
}

extern "C" void kernel_launch(void* const* d_in, const int* in_sizes, int n_in,
                              void* d_out, int out_size, void* d_ws, size_t ws_size,
                              hipStream_t stream) {
  const float* x    = (const float*)d_in[0];
  const float* Wg1  = (const float*)d_in[1];
  const float* Wg2  = (const float*)d_in[2];
  const float* Win  = (const float*)d_in[3];
  const float* Wout = (const float*)d_in[4];
  float* out = (float*)d_out;

  char* ws = (char*)d_ws;
  size_t off = 0;
  auto alloc = [&](size_t bytes) -> void* {
    void* p = ws + off;
    off = (off + bytes + 255) & ~(size_t)255;
    return p;
  };
  int*   counts  = (int*)alloc(32);
  int*   offsets = (int*)alloc(64);
  int*   cursors = (int*)alloc(32);
  float* lossacc = (float*)alloc(64);   // header ends well before 1024 bytes
  int*   top_i   = (int*)alloc((size_t)NPAIR * 4);
  float* top_v   = (float*)alloc((size_t)NPAIR * 4);
  int*   ptok    = (int*)alloc((size_t)NPAIR * 4);
  float* pgate   = (float*)alloc((size_t)NPAIR * 4);
  int*   rowof   = (int*)alloc((size_t)NPAIR * 4);
  float* hg      = (float*)alloc((size_t)N_TOK * GDIM * 4);
  _Float16* xh    = (_Float16*)alloc((size_t)N_TOK * DIM * 2);
  _Float16* WinT  = (_Float16*)alloc((size_t)NEXP * DIM * HID * 2);
  _Float16* WoutT = (_Float16*)alloc((size_t)NEXP * DIM * HID * 2);
  _Float16* hb    = (_Float16*)alloc((size_t)HB_ROWS * HID * 2);
  // yb[NPAIR][DIM] fp16 (33.5 MB) aliases xh+WinT (16.7+16.7 MB, contiguous):
  // both are dead by the time gemm2 runs (stream-ordered after gemm1).
  _Float16* yb = xh;
  (void)ws_size; (void)in_sizes; (void)n_in;

  hipMemsetAsync(d_ws, 0, 1024, stream);  // counts/cursors/lossacc zero every call

  cast_x_kernel<<<N_TOK * DIM / (8 * 256), 256, 0, stream>>>(x, xh);
  cast_wT_kernel<<<dim3(16, 16, 16), 256, 0, stream>>>(Win, Wout, WinT, WoutT);
  gemm_h_kernel<<<dim3(N_TOK / 64, GDIM / 64), 256, 0, stream>>>(x, Wg1, hg);
  gate_kernel<<<N_TOK / 8, 256, 0, stream>>>(hg, Wg2, top_i, top_v, lossacc, counts);
  scan_kernel<<<1, 32, 0, stream>>>(counts, offsets);
  fill_kernel<<<N_TOK / 256, 256, 0, stream>>>(top_i, top_v, offsets, cursors, ptok, pgate, rowof);
  gemm1_kernel<<<dim3(MT_MAX, HID / 128), 256, 0, stream>>>(xh, WinT, hb, offsets, ptok);
  gemm2_kernel<<<dim3(MT_MAX, DIM / 128), 256, 0, stream>>>(hb, WoutT, yb, offsets, pgate);
  combine_kernel<<<N_TOK / 2, 256, 0, stream>>>(yb, rowof, out);
  loss_kernel<<<1, 64, 0, stream>>>(lossacc, out + (size_t)N_TOK * DIM);
}